// Round 1
// baseline (192.606 us; speedup 1.0000x reference)
//
#include <hip/hip_runtime.h>

#define N_NODES 100000
#define N_EDGES 800000
#define IN_FEATS 128
#define NUM_CLASSES 64

#define NSB    98       // super-buckets: dst >> 10 (1024 nodes each)
#define SCAP   9216     // staging slots per super-bucket (lambda=8192, +11 sigma)
#define BINCAP 56       // LDS bin slots per (block, sb): lambda=20.9 (+fallback path)
#define NBKT   12500    // final buckets: 8 dst nodes each
#define NBKT_PAD (NSB * 128)   // 12544: incl. phantom buckets of sb=97
#define PB_CAP 128      // entries per bucket, node-grouped (lambda=64, +8 sigma, P(ovf)~2e-7)

// Fused K1 grid: every 5th block is a scatter_p1 block -> concurrent with gemm.
#define K1_GRID 1955    // 391 groups of 5: 4 gemm-role + 1 p1-role

typedef short bf16x8 __attribute__((ext_vector_type(8)));
typedef float f32x4  __attribute__((ext_vector_type(4)));

static __device__ __forceinline__ unsigned short f2bf(float f) {
    unsigned u = __float_as_uint(f);
    unsigned r = (u + 0x7fffu + ((u >> 16) & 1u)) >> 16;
    return (unsigned short)r;
}
static __device__ __forceinline__ float bf2f(unsigned short v) {
    return __uint_as_float(((unsigned)v) << 16);
}

// ---------------------------------------------------------------------------
// gemm role: y16 = bf16(x @ W^T) via MFMA 16x16x32 bf16. (R4-proven body)
// smem usage: Wf 16384 B + Xs 17408 B = 33792 B.
// ---------------------------------------------------------------------------
static __device__ __forceinline__ void gemm_body(char* smem, int gid,
                                                 const float* __restrict__ x,
                                                 const float* __restrict__ W,
                                                 unsigned short* __restrict__ y16) {
    const long base = (long)gid * 64;
    if (base >= N_NODES) return;   // uniform per block

    unsigned short* Wf = (unsigned short*)smem;                    // [4*4*64*8]
    typedef unsigned short XsRow[136];
    XsRow* Xs = (XsRow*)(smem + 16384);                            // [64][136]

    const int tid = threadIdx.x;

    for (int i = tid; i < 4 * 4 * 64 * 8; i += 256) {
        const int j    = i & 7;
        const int lane = (i >> 3) & 63;
        const int t    = (i >> 9) & 3;
        const int s    = i >> 11;
        const int k = s * 32 + ((lane >> 4) << 3) + j;
        const int c = t * 16 + (lane & 15);
        Wf[i] = f2bf(W[c * IN_FEATS + k]);
    }

#pragma unroll
    for (int it = 0; it < 8; ++it) {
        const int i   = tid + it * 256;
        const int row = i >> 5;
        const int c4  = (i & 31) << 2;
        const long node = base + row;
        float4 v = make_float4(0.f, 0.f, 0.f, 0.f);
        if (node < N_NODES) v = *(const float4*)&x[node * IN_FEATS + c4];
        ushort4 w4;
        w4.x = f2bf(v.x); w4.y = f2bf(v.y); w4.z = f2bf(v.z); w4.w = f2bf(v.w);
        *(ushort4*)&Xs[row][c4] = w4;
    }
    __syncthreads();

    const int wave = tid >> 6;
    const int lane = tid & 63;
    const long nb  = base + wave * 16;

    bf16x8 wf[4][4];
#pragma unroll
    for (int s = 0; s < 4; ++s)
#pragma unroll
        for (int t = 0; t < 4; ++t)
            wf[s][t] = *(const bf16x8*)&Wf[(((s * 4 + t) * 64) + lane) * 8];

    f32x4 acc[4];
#pragma unroll
    for (int t = 0; t < 4; ++t) acc[t] = (f32x4){0.f, 0.f, 0.f, 0.f};

    const int m  = lane & 15;
    const int kq = lane >> 4;
    const unsigned short* arow = &Xs[wave * 16 + m][kq * 8];

#pragma unroll
    for (int s = 0; s < 4; ++s) {
        bf16x8 af = *(const bf16x8*)(arow + s * 32);
#pragma unroll
        for (int t = 0; t < 4; ++t)
            acc[t] = __builtin_amdgcn_mfma_f32_16x16x32_bf16(af, wf[s][t], acc[t], 0, 0, 0);
    }

    const int ccol  = lane & 15;
    const int rbase = (lane >> 4) << 2;
#pragma unroll
    for (int t = 0; t < 4; ++t) {
#pragma unroll
        for (int r = 0; r < 4; ++r) {
            const long n2 = nb + rbase + r;
            if (n2 < N_NODES)
                y16[n2 * NUM_CLASSES + t * 16 + ccol] = f2bf(acc[t][r]);
        }
    }
}

// ---------------------------------------------------------------------------
// p1 role: LDS-bin 2048 edges by super-bucket, one global atomic per
// (block, sb) reserves contiguous staging slots. (R7-proven body)
// smem usage: bins 21952 B + bcnt 392 B + bbase 392 B = 22736 B <= 33792.
// ---------------------------------------------------------------------------
static __device__ __forceinline__ void p1_body(char* smem, int p1id,
                                               const int* __restrict__ esrc,
                                               const int* __restrict__ edst,
                                               int* __restrict__ sbcur,
                                               unsigned* __restrict__ stage) {
    typedef unsigned BinRow[BINCAP];
    BinRow* bins = (BinRow*)smem;                       // [NSB][BINCAP]
    int* bcnt  = (int*)(smem + 21952);
    int* bbase = (int*)(smem + 21952 + 392);

    const int tid = threadIdx.x;
    for (int i = tid; i < NSB; i += 256) bcnt[i] = 0;
    __syncthreads();

    const int e0 = p1id * 2048;
#pragma unroll
    for (int it = 0; it < 8; ++it) {
        const int e = e0 + it * 256 + tid;
        if (e < N_EDGES) {
            const unsigned s  = (unsigned)esrc[e];
            const unsigned d  = (unsigned)edst[e];
            const unsigned sb = d >> 10;
            const unsigned pk = s | ((d & 1023u) << 17);
            const int p = atomicAdd(&bcnt[sb], 1);
            if (p < BINCAP) {
                bins[sb][p] = pk;
            } else {                       // rare LDS-bin overflow: direct global
                const int gp = atomicAdd(&sbcur[sb << 4], 1);
                if (gp < SCAP) stage[sb * SCAP + gp] = pk;
            }
        }
    }
    __syncthreads();

    if (tid < NSB) {
        const int c = min(bcnt[tid], BINCAP);
        bcnt[tid]  = c;
        bbase[tid] = atomicAdd(&sbcur[tid << 4], c);
    }
    __syncthreads();

    for (int i = tid; i < NSB * BINCAP; i += 256) {
        const int sb = i / BINCAP;
        const int k  = i - sb * BINCAP;
        if (k < bcnt[sb]) {
            const int pos = bbase[sb] + k;
            if (pos < SCAP) stage[sb * SCAP + pos] = bins[sb][k];
        }
    }
}

// ---------------------------------------------------------------------------
// K1: fused gemm + scatter_p1, roles interleaved (bid%5==4 -> p1) so both
// kinds are co-resident: MFMA/LDS-bound gemm overlaps latency-bound p1.
// ---------------------------------------------------------------------------
__global__ __launch_bounds__(256) void k1_gemm_scatter(const float* __restrict__ x,
                                                       const float* __restrict__ W,
                                                       unsigned short* __restrict__ y16,
                                                       const int* __restrict__ esrc,
                                                       const int* __restrict__ edst,
                                                       int* __restrict__ sbcur,
                                                       unsigned* __restrict__ stage) {
    __shared__ __align__(16) char smem[33792];
    const int bid = blockIdx.x;
    const int r   = bid % 5;
    if (r == 4) {
        p1_body(smem, bid / 5, esrc, edst, sbcur, stage);
    } else {
        gemm_body(smem, (bid / 5) * 4 + r, x, W, y16);
    }
}

// ---------------------------------------------------------------------------
// Scatter pass 2 (v2): two-scan count/prefix/place producing NODE-GROUPED
// dense per-bucket lists. 4 blocks per sb; block (sb,q) owns buckets with
// (fb&3)==q, so each bucket has exactly one writer -> single dense list,
// entries grouped by dst node, cnt_g[gnode] = exact in-degree.
// ---------------------------------------------------------------------------
__global__ __launch_bounds__(256) void scatter_p2(const unsigned* __restrict__ stage,
                                                  const int* __restrict__ sbcur,
                                                  unsigned* __restrict__ pairs,
                                                  int* __restrict__ cnt_g) {
    __shared__ int lcnt[256];   // 32 owned buckets x 8 nodes
    __shared__ int loff[256];   // placement cursors (start offsets)
    const int sb  = blockIdx.x >> 2;
    const int q   = blockIdx.x & 3;
    const int tid = threadIdx.x;

    lcnt[tid] = 0;
    __syncthreads();

    const int ecnt = min(sbcur[sb << 4], SCAP);
    const unsigned* sp = stage + (size_t)sb * SCAP;

    // scan 1: per-node counts of owned buckets
    for (int i = tid; i < ecnt; i += 256) {
        const unsigned pk   = sp[i];
        const unsigned dlow = pk >> 17;
        const unsigned fb   = dlow >> 3;
        if ((fb & 3u) == (unsigned)q)
            atomicAdd(&lcnt[(int)(((fb >> 2) << 3) + (dlow & 7u))], 1);
    }
    __syncthreads();

    // prefix within each owned bucket; publish per-node degrees
    if (tid < 32) {
        const int fb     = (tid << 2) + q;           // global fb within sb
        const int gnode0 = (sb << 10) + (fb << 3);
        int run = 0;
#pragma unroll
        for (int k = 0; k < 8; ++k) {
            const int li = (tid << 3) + k;
            const int c  = lcnt[li];
            const int st = min(run, PB_CAP);
            const int en = min(run + c, PB_CAP);
            loff[li] = st;
            cnt_g[gnode0 + k] = en - st;
            run += c;
        }
    }
    __syncthreads();

    // scan 2: place, grouped by node (src-only payload, 17 bits)
    for (int i = tid; i < ecnt; i += 256) {
        const unsigned pk   = sp[i];
        const unsigned dlow = pk >> 17;
        const unsigned fb   = dlow >> 3;
        if ((fb & 3u) == (unsigned)q) {
            const int li = (int)(((fb >> 2) << 3) + (dlow & 7u));
            const int r  = atomicAdd(&loff[li], 1);
            if (r < PB_CAP)
                pairs[((size_t)(sb << 7) + fb) * PB_CAP + r] = pk & 0x1FFFFu;
        }
    }
}

// ---------------------------------------------------------------------------
// Gather (v2): one WAVE per bucket, lane == output class, ZERO LDS.
// Node-grouped lists mean a single register accumulator per node: per edge
// ~2 VALU + ~3 SALU + one coalesced 128 B y16 row load (uniform SGPR base
// via readlane + fixed lane*2 voffset). No slab zeroing, no barriers, no
// cross-wave reduce, no LDS bank traffic. 4 buckets per 256-thread block.
// ---------------------------------------------------------------------------
__global__ __launch_bounds__(256) void gather_node(const unsigned short* __restrict__ y16,
                                                   const unsigned* __restrict__ pairs,
                                                   const int* __restrict__ cnt_g,
                                                   const float* __restrict__ b,
                                                   float* __restrict__ out) {
    const int tid  = threadIdx.x;
    const int wave = tid >> 6;
    const int lane = tid & 63;
    const int bkt  = blockIdx.x * 4 + wave;      // < 12500 (grid is exact)
    const int g0   = bkt << 3;                   // first dst node of bucket

    const unsigned* pb = pairs + (size_t)bkt * PB_CAP;
    const int r0 = (int)pb[lane];                // entries 0..63
    const int r1 = (int)pb[64 + lane];           // entries 64..127
    int cc = 0;
    if (lane < 8) cc = cnt_g[g0 + lane];         // per-node degrees
    const float bl = b[lane];

    int off = 0;
#pragma unroll
    for (int n = 0; n < 8; ++n) {
        const int c = __builtin_amdgcn_readlane(cc, n);   // uniform degree
        float acc = 0.f;
        const int e0 = min(c, max(0, 64 - off));          // entries served by r0
        const int s1 = off + e0 - 64;                     // r1 start (if any)
        const int e1 = c - e0;
#pragma unroll 4
        for (int j = 0; j < e0; ++j) {
            const unsigned p = (unsigned)__builtin_amdgcn_readlane(r0, off + j);
            acc += bf2f(y16[(size_t)p * NUM_CLASSES + lane]);
        }
#pragma unroll 4
        for (int j = 0; j < e1; ++j) {
            const unsigned p = (unsigned)__builtin_amdgcn_readlane(r1, s1 + j);
            acc += bf2f(y16[(size_t)p * NUM_CLASSES + lane]);
        }
        off += c;
        const size_t v = (size_t)(g0 + n);
        const float self = bf2f(y16[v * NUM_CLASSES + lane]);
        out[v * NUM_CLASSES + lane] = (acc + self) / (float)(c + 1) + bl;
    }
}

extern "C" void kernel_launch(void* const* d_in, const int* in_sizes, int n_in,
                              void* d_out, int out_size, void* d_ws, size_t ws_size,
                              hipStream_t stream) {
    const float* x    = (const float*)d_in[0];
    const int*   esrc = (const int*)d_in[1];
    const int*   edst = (const int*)d_in[2];
    const float* W    = (const float*)d_in[3];
    const float* b    = (const float*)d_in[4];
    float* out = (float*)d_out;

    // Workspace layout (~23.3 MB used; ws_size is 256 MiB per profile).
    char* p = (char*)d_ws;
    unsigned short* y16 = (unsigned short*)p;  p += (size_t)N_NODES * NUM_CLASSES * 2; // 12.8 MB
    unsigned* stage     = (unsigned*)p;        p += (size_t)NSB * SCAP * 4;            // 3.6 MB
    unsigned* pairs     = (unsigned*)p;        p += (size_t)NBKT_PAD * PB_CAP * 4;     // 6.4 MB
    int* cnt_g          = (int*)p;             p += (size_t)NBKT_PAD * 8 * 4;          // 401 KB
    int* sbcur          = (int*)p;             p += (size_t)NSB * 16 * 4;              // 6.3 KB

    // Zero only the 98 line-padded super-bucket cursors (needed before p1 role).
    hipMemsetAsync(sbcur, 0, (size_t)NSB * 16 * 4, stream);

    // Fused gemm + scatter_p1 (concurrent roles).
    k1_gemm_scatter<<<K1_GRID, 256, 0, stream>>>(x, W, y16, esrc, edst, sbcur, stage);

    // Rank staged edges into node-grouped dense bucket lists.
    scatter_p2<<<NSB * 4, 256, 0, stream>>>(stage, sbcur, pairs, cnt_g);

    // Register-only gather + fused normalize/bias. 3125 blocks x 4 waves x 8 nodes.
    gather_node<<<NBKT / 4, 256, 0, stream>>>(y16, pairs, cnt_g, b, out);
}

// Round 2
// 158.104 us; speedup vs baseline: 1.2182x; 1.2182x over previous
//
#include <hip/hip_runtime.h>

#define N_NODES 100000
#define N_EDGES 800000
#define IN_FEATS 128
#define NUM_CLASSES 64

#define NSB    98       // super-buckets: dst >> 10 (1024 nodes each)
#define SCAP   9216     // staging slots per super-bucket (lambda=8192, +11 sigma)
#define BINCAP 56       // LDS bin slots per (block, sb): lambda=20.9 (+fallback path)
#define NBKT   12500    // final buckets: 8 dst nodes each
#define NBKT_PAD (NSB * 128)   // 12544: incl. phantom buckets of sb=97
#define PB_CAP 128      // entries per bucket, node-grouped (lambda=64, +8 sigma)

// Fused K1 grid: every 5th block is a scatter_p1 block -> concurrent with gemm.
#define K1_GRID 1955    // 391 groups of 5: 4 gemm-role + 1 p1-role

typedef short bf16x8 __attribute__((ext_vector_type(8)));
typedef float f32x4  __attribute__((ext_vector_type(4)));

static __device__ __forceinline__ unsigned short f2bf(float f) {
    unsigned u = __float_as_uint(f);
    unsigned r = (u + 0x7fffu + ((u >> 16) & 1u)) >> 16;
    return (unsigned short)r;
}
static __device__ __forceinline__ float bf2f(unsigned short v) {
    return __uint_as_float(((unsigned)v) << 16);
}

// ---------------------------------------------------------------------------
// gemm role: y16 = bf16(x @ W^T) via MFMA 16x16x32 bf16. (R4-proven body)
// smem usage: Wf 16384 B + Xs 17408 B = 33792 B.
// ---------------------------------------------------------------------------
static __device__ __forceinline__ void gemm_body(char* smem, int gid,
                                                 const float* __restrict__ x,
                                                 const float* __restrict__ W,
                                                 unsigned short* __restrict__ y16) {
    const long base = (long)gid * 64;
    if (base >= N_NODES) return;   // uniform per block

    unsigned short* Wf = (unsigned short*)smem;                    // [4*4*64*8]
    typedef unsigned short XsRow[136];
    XsRow* Xs = (XsRow*)(smem + 16384);                            // [64][136]

    const int tid = threadIdx.x;

    for (int i = tid; i < 4 * 4 * 64 * 8; i += 256) {
        const int j    = i & 7;
        const int lane = (i >> 3) & 63;
        const int t    = (i >> 9) & 3;
        const int s    = i >> 11;
        const int k = s * 32 + ((lane >> 4) << 3) + j;
        const int c = t * 16 + (lane & 15);
        Wf[i] = f2bf(W[c * IN_FEATS + k]);
    }

#pragma unroll
    for (int it = 0; it < 8; ++it) {
        const int i   = tid + it * 256;
        const int row = i >> 5;
        const int c4  = (i & 31) << 2;
        const long node = base + row;
        float4 v = make_float4(0.f, 0.f, 0.f, 0.f);
        if (node < N_NODES) v = *(const float4*)&x[node * IN_FEATS + c4];
        ushort4 w4;
        w4.x = f2bf(v.x); w4.y = f2bf(v.y); w4.z = f2bf(v.z); w4.w = f2bf(v.w);
        *(ushort4*)&Xs[row][c4] = w4;
    }
    __syncthreads();

    const int wave = tid >> 6;
    const int lane = tid & 63;
    const long nb  = base + wave * 16;

    bf16x8 wf[4][4];
#pragma unroll
    for (int s = 0; s < 4; ++s)
#pragma unroll
        for (int t = 0; t < 4; ++t)
            wf[s][t] = *(const bf16x8*)&Wf[(((s * 4 + t) * 64) + lane) * 8];

    f32x4 acc[4];
#pragma unroll
    for (int t = 0; t < 4; ++t) acc[t] = (f32x4){0.f, 0.f, 0.f, 0.f};

    const int m  = lane & 15;
    const int kq = lane >> 4;
    const unsigned short* arow = &Xs[wave * 16 + m][kq * 8];

#pragma unroll
    for (int s = 0; s < 4; ++s) {
        bf16x8 af = *(const bf16x8*)(arow + s * 32);
#pragma unroll
        for (int t = 0; t < 4; ++t)
            acc[t] = __builtin_amdgcn_mfma_f32_16x16x32_bf16(af, wf[s][t], acc[t], 0, 0, 0);
    }

    const int ccol  = lane & 15;
    const int rbase = (lane >> 4) << 2;
#pragma unroll
    for (int t = 0; t < 4; ++t) {
#pragma unroll
        for (int r = 0; r < 4; ++r) {
            const long n2 = nb + rbase + r;
            if (n2 < N_NODES)
                y16[n2 * NUM_CLASSES + t * 16 + ccol] = f2bf(acc[t][r]);
        }
    }
}

// ---------------------------------------------------------------------------
// p1 role: LDS-bin 2048 edges by super-bucket, one global atomic per
// (block, sb) reserves contiguous staging slots. (R7-proven body)
// smem usage: bins 21952 B + bcnt 392 B + bbase 392 B = 22736 B <= 33792.
// ---------------------------------------------------------------------------
static __device__ __forceinline__ void p1_body(char* smem, int p1id,
                                               const int* __restrict__ esrc,
                                               const int* __restrict__ edst,
                                               int* __restrict__ sbcur,
                                               unsigned* __restrict__ stage) {
    typedef unsigned BinRow[BINCAP];
    BinRow* bins = (BinRow*)smem;                       // [NSB][BINCAP]
    int* bcnt  = (int*)(smem + 21952);
    int* bbase = (int*)(smem + 21952 + 392);

    const int tid = threadIdx.x;
    for (int i = tid; i < NSB; i += 256) bcnt[i] = 0;
    __syncthreads();

    const int e0 = p1id * 2048;
#pragma unroll
    for (int it = 0; it < 8; ++it) {
        const int e = e0 + it * 256 + tid;
        if (e < N_EDGES) {
            const unsigned s  = (unsigned)esrc[e];
            const unsigned d  = (unsigned)edst[e];
            const unsigned sb = d >> 10;
            const unsigned pk = s | ((d & 1023u) << 17);
            const int p = atomicAdd(&bcnt[sb], 1);
            if (p < BINCAP) {
                bins[sb][p] = pk;
            } else {                       // rare LDS-bin overflow: direct global
                const int gp = atomicAdd(&sbcur[sb << 4], 1);
                if (gp < SCAP) stage[sb * SCAP + gp] = pk;
            }
        }
    }
    __syncthreads();

    if (tid < NSB) {
        const int c = min(bcnt[tid], BINCAP);
        bcnt[tid]  = c;
        bbase[tid] = atomicAdd(&sbcur[tid << 4], c);
    }
    __syncthreads();

    for (int i = tid; i < NSB * BINCAP; i += 256) {
        const int sb = i / BINCAP;
        const int k  = i - sb * BINCAP;
        if (k < bcnt[sb]) {
            const int pos = bbase[sb] + k;
            if (pos < SCAP) stage[sb * SCAP + pos] = bins[sb][k];
        }
    }
}

// ---------------------------------------------------------------------------
// K1: fused gemm + scatter_p1, roles interleaved (bid%5==4 -> p1).
// ---------------------------------------------------------------------------
__global__ __launch_bounds__(256) void k1_gemm_scatter(const float* __restrict__ x,
                                                       const float* __restrict__ W,
                                                       unsigned short* __restrict__ y16,
                                                       const int* __restrict__ esrc,
                                                       const int* __restrict__ edst,
                                                       int* __restrict__ sbcur,
                                                       unsigned* __restrict__ stage) {
    __shared__ __align__(16) char smem[33792];
    const int bid = blockIdx.x;
    const int r   = bid % 5;
    if (r == 4) {
        p1_body(smem, bid / 5, esrc, edst, sbcur, stage);
    } else {
        gemm_body(smem, (bid / 5) * 4 + r, x, W, y16);
    }
}

// ---------------------------------------------------------------------------
// Scatter pass 2: two-scan count/prefix/place producing NODE-GROUPED dense
// per-bucket lists. 4 blocks per sb; block (sb,q) owns buckets (fb&3)==q.
// cnt_g[gnode] = exact (clipped) in-degree.
// ---------------------------------------------------------------------------
__global__ __launch_bounds__(256) void scatter_p2(const unsigned* __restrict__ stage,
                                                  const int* __restrict__ sbcur,
                                                  unsigned* __restrict__ pairs,
                                                  int* __restrict__ cnt_g) {
    __shared__ int lcnt[256];   // 32 owned buckets x 8 nodes
    __shared__ int loff[256];   // placement cursors (start offsets)
    const int sb  = blockIdx.x >> 2;
    const int q   = blockIdx.x & 3;
    const int tid = threadIdx.x;

    lcnt[tid] = 0;
    __syncthreads();

    const int ecnt = min(sbcur[sb << 4], SCAP);
    const unsigned* sp = stage + (size_t)sb * SCAP;

    // scan 1: per-node counts of owned buckets
    for (int i = tid; i < ecnt; i += 256) {
        const unsigned pk   = sp[i];
        const unsigned dlow = pk >> 17;
        const unsigned fb   = dlow >> 3;
        if ((fb & 3u) == (unsigned)q)
            atomicAdd(&lcnt[(int)(((fb >> 2) << 3) + (dlow & 7u))], 1);
    }
    __syncthreads();

    // prefix within each owned bucket; publish per-node degrees
    if (tid < 32) {
        const int fb     = (tid << 2) + q;           // global fb within sb
        const int gnode0 = (sb << 10) + (fb << 3);
        int run = 0;
#pragma unroll
        for (int k = 0; k < 8; ++k) {
            const int li = (tid << 3) + k;
            const int c  = lcnt[li];
            const int st = min(run, PB_CAP);
            const int en = min(run + c, PB_CAP);
            loff[li] = st;
            cnt_g[gnode0 + k] = en - st;
            run += c;
        }
    }
    __syncthreads();

    // scan 2: place, grouped by node (src-only payload, 17 bits)
    for (int i = tid; i < ecnt; i += 256) {
        const unsigned pk   = sp[i];
        const unsigned dlow = pk >> 17;
        const unsigned fb   = dlow >> 3;
        if ((fb & 3u) == (unsigned)q) {
            const int li = (int)(((fb >> 2) << 3) + (dlow & 7u));
            const int r  = atomicAdd(&loff[li], 1);
            if (r < PB_CAP)
                pairs[((size_t)(sb << 7) + fb) * PB_CAP + r] = pk & 0x1FFFFu;
        }
    }
}

// ---------------------------------------------------------------------------
// Gather (v3): one WAVE per bucket; lane = (node g = lane>>3, class-octet
// q = lane&7). All 8 dst nodes of a bucket accumulate CONCURRENTLY in fixed
// registers (8 independent dep-chains per wave). Edge src indices come from
// the pre-loaded r0/r1 bucket list via ds_bpermute (no dependent global
// p-load). Uniform edge loop to maxc, unrolled x4 with clamp+mask -> 4
// independent 16 B row-loads in flight per batch. ZERO LDS, ~40 VGPR.
// ---------------------------------------------------------------------------
__global__ __launch_bounds__(256) void gather_node(const unsigned short* __restrict__ y16,
                                                   const unsigned* __restrict__ pairs,
                                                   const int* __restrict__ cnt_g,
                                                   const float* __restrict__ b,
                                                   float* __restrict__ out) {
    const int tid  = threadIdx.x;
    const int wave = tid >> 6;
    const int lane = tid & 63;
    const int bkt  = blockIdx.x * 4 + wave;      // < 12500 (grid is exact)
    const int g0   = bkt << 3;                   // first dst node of bucket

    const int g = lane >> 3;                     // node within bucket (0..7)
    const int q = lane & 7;                      // class octet (classes q*8..q*8+7)

    // per-node degrees in lanes 0..7
    int cc = 0;
    if (lane < 8) cc = cnt_g[g0 + lane];

    // exclusive prefix among lanes 0..7
    int off = 0;
#pragma unroll
    for (int k = 0; k < 7; ++k) {
        const int v = __shfl(cc, k);
        if (lane > k) off += v;
    }

    // per-lane group values (uniform within each 8-lane group)
    const int myc   = __shfl(cc, g);
    const int myoff = __shfl(off, g);

    // wave-uniform max degree
    int mc = cc;
#pragma unroll
    for (int s = 1; s < 8; s <<= 1) mc = max(mc, __shfl_xor(mc, s));
    const int maxc = __builtin_amdgcn_readfirstlane(mc);

    // pre-load the whole bucket list into registers
    const unsigned* pb = pairs + (size_t)bkt * PB_CAP;
    const int r0 = (int)pb[lane];
    const int r1 = (int)pb[64 + lane];

    f32x4 accA = {0.f, 0.f, 0.f, 0.f};
    f32x4 accB = {0.f, 0.f, 0.f, 0.f};

    for (int j = 0; j < maxc; j += 4) {
        bf16x8 h[4];
        int     ok[4];
#pragma unroll
        for (int t = 0; t < 4; ++t) {
            const int jt  = j + t;
            const int idx = myoff + max(min(jt, myc - 1), 0);   // clamped in-window
            const int plo = __shfl(r0, idx);
            const int phi = __shfl(r1, idx - 64);
            const unsigned pv = (unsigned)((idx < 64) ? plo : phi) & 0x1FFFFu;
            h[t]  = *(const bf16x8*)&y16[(size_t)pv * NUM_CLASSES + q * 8];
            ok[t] = (jt < myc);
        }
#pragma unroll
        for (int t = 0; t < 4; ++t) {
            if (ok[t]) {
#pragma unroll
                for (int k = 0; k < 4; ++k) accA[k] += bf2f((unsigned short)h[t][k]);
#pragma unroll
                for (int k = 0; k < 4; ++k) accB[k] += bf2f((unsigned short)h[t][4 + k]);
            }
        }
    }

    // epilogue: self + normalize + bias; each lane writes 8 consecutive floats
    const size_t v = (size_t)(g0 + g);
    const bf16x8 hs = *(const bf16x8*)&y16[v * NUM_CLASSES + q * 8];
    const float inv = 1.0f / (float)(myc + 1);
    const float4 b0 = *(const float4*)&b[q * 8];
    const float4 b1 = *(const float4*)&b[q * 8 + 4];

    float4 o0, o1;
    o0.x = (accA[0] + bf2f((unsigned short)hs[0])) * inv + b0.x;
    o0.y = (accA[1] + bf2f((unsigned short)hs[1])) * inv + b0.y;
    o0.z = (accA[2] + bf2f((unsigned short)hs[2])) * inv + b0.z;
    o0.w = (accA[3] + bf2f((unsigned short)hs[3])) * inv + b0.w;
    o1.x = (accB[0] + bf2f((unsigned short)hs[4])) * inv + b1.x;
    o1.y = (accB[1] + bf2f((unsigned short)hs[5])) * inv + b1.y;
    o1.z = (accB[2] + bf2f((unsigned short)hs[6])) * inv + b1.z;
    o1.w = (accB[3] + bf2f((unsigned short)hs[7])) * inv + b1.w;

    *(float4*)&out[v * NUM_CLASSES + q * 8]     = o0;
    *(float4*)&out[v * NUM_CLASSES + q * 8 + 4] = o1;
}

extern "C" void kernel_launch(void* const* d_in, const int* in_sizes, int n_in,
                              void* d_out, int out_size, void* d_ws, size_t ws_size,
                              hipStream_t stream) {
    const float* x    = (const float*)d_in[0];
    const int*   esrc = (const int*)d_in[1];
    const int*   edst = (const int*)d_in[2];
    const float* W    = (const float*)d_in[3];
    const float* b    = (const float*)d_in[4];
    float* out = (float*)d_out;

    // Workspace layout (~23.3 MB used; ws_size is 256 MiB per profile).
    char* p = (char*)d_ws;
    unsigned short* y16 = (unsigned short*)p;  p += (size_t)N_NODES * NUM_CLASSES * 2; // 12.8 MB
    unsigned* stage     = (unsigned*)p;        p += (size_t)NSB * SCAP * 4;            // 3.6 MB
    unsigned* pairs     = (unsigned*)p;        p += (size_t)NBKT_PAD * PB_CAP * 4;     // 6.4 MB
    int* cnt_g          = (int*)p;             p += (size_t)NBKT_PAD * 8 * 4;          // 401 KB
    int* sbcur          = (int*)p;             p += (size_t)NSB * 16 * 4;              // 6.3 KB

    // Zero only the 98 line-padded super-bucket cursors (needed before p1 role).
    hipMemsetAsync(sbcur, 0, (size_t)NSB * 16 * 4, stream);

    // Fused gemm + scatter_p1 (concurrent roles).
    k1_gemm_scatter<<<K1_GRID, 256, 0, stream>>>(x, W, y16, esrc, edst, sbcur, stage);

    // Rank staged edges into node-grouped dense bucket lists.
    scatter_p2<<<NSB * 4, 256, 0, stream>>>(stage, sbcur, pairs, cnt_g);

    // Register-only gather + fused normalize/bias. 3125 blocks x 4 waves x 8 nodes.
    gather_node<<<NBKT / 4, 256, 0, stream>>>(y16, pairs, cnt_g, b, out);
}